// Round 3
// baseline (2648.469 us; speedup 1.0000x reference)
//
#include <hip/hip_runtime.h>
#include <math.h>

#define U_N 100000
#define I_N 50000
#define DD  64
#define BB  8192
#define TT  30
#define N_EUI 1600000
#define N_EII 800000
#define LN_EPS_ 1e-5f
#define BEH_SCALE_ 0.35f
#define REG_COEF_ 1e-4f

__device__ __forceinline__ float wave_sum64(float v) {
#pragma unroll
  for (int o = 32; o > 0; o >>= 1) v += __shfl_xor(v, o, 64);
  return v;
}

__device__ __forceinline__ float rdlane(float v, int k) {
  return __int_as_float(__builtin_amdgcn_readlane(__float_as_int(v), k));
}

// ---------------- CSR build ----------------

__global__ __launch_bounds__(256) void hist_kernel(
    const int* __restrict__ rows, int nE, int* __restrict__ cnt) {
  for (long e = (long)blockIdx.x * blockDim.x + threadIdx.x; e < nE;
       e += (long)gridDim.x * blockDim.x)
    atomicAdd(&cnt[rows[e]], 1);
}

__global__ __launch_bounds__(1024) void ex_scan(
    const int* __restrict__ cnt, int n, int* __restrict__ offs,
    int* __restrict__ cursor) {
  __shared__ int part[1024];
  const int tid = threadIdx.x;
  const int chunk = (n + 1023) / 1024;
  const int lo = tid * chunk;
  const int hi = min(lo + chunk, n);
  int s = 0;
  for (int i = lo; i < hi; ++i) s += cnt[i];
  part[tid] = s;
  __syncthreads();
  for (int off = 1; off < 1024; off <<= 1) {
    int v = part[tid];
    int add = (tid >= off) ? part[tid - off] : 0;
    __syncthreads();
    part[tid] = v + add;
    __syncthreads();
  }
  int base = (tid == 0) ? 0 : part[tid - 1];
  for (int i = lo; i < hi; ++i) {
    int c = cnt[i];  // read BEFORE writing (cnt aliases cursor)
    offs[i] = base;
    cursor[i] = base;
    base += c;
  }
  if (tid == 0) offs[n] = part[1023];
}

__global__ __launch_bounds__(256) void csr_fill(
    const int* __restrict__ drows, const int* __restrict__ srows,
    const float* __restrict__ vals, int nE, int* __restrict__ cursor,
    int2* __restrict__ pairs) {
  for (long e = (long)blockIdx.x * blockDim.x + threadIdx.x; e < nE;
       e += (long)gridDim.x * blockDim.x) {
    int d = drows[e];
    int pos = atomicAdd(&cursor[d], 1);
    pairs[pos] = make_int2(srows[e], __float_as_int(vals[e]));
  }
}

// ---------------- fused GNN layers ----------------

__global__ __launch_bounds__(256) void gnn_user_layer(
    const float* __restrict__ cur_u, const float* __restrict__ src_it,
    const int* __restrict__ offs, const int2* __restrict__ pairs,
    const float* __restrict__ W, const float* __restrict__ bias,
    float* __restrict__ out) {
  __shared__ float Wl[DD * DD];
  for (int i = threadIdx.x; i < DD * DD; i += blockDim.x) Wl[i] = W[i];
  __syncthreads();
  const int lane = threadIdx.x & 63;
  const float bn = bias[lane];
  long wid = ((long)blockIdx.x * blockDim.x + threadIdx.x) >> 6;
  long nw = ((long)gridDim.x * blockDim.x) >> 6;
  for (long r = wid; r < U_N; r += nw) {
    float acc = cur_u[r * DD + lane], acc2 = 0.f;
    int j = offs[r], j1 = offs[r + 1];
    for (; j + 1 < j1; j += 2) {
      int2 p0 = pairs[j], p1 = pairs[j + 1];
      acc = fmaf(__int_as_float(p0.y), src_it[(long)p0.x * DD + lane], acc);
      acc2 = fmaf(__int_as_float(p1.y), src_it[(long)p1.x * DD + lane], acc2);
    }
    if (j < j1) {
      int2 p = pairs[j];
      acc = fmaf(__int_as_float(p.y), src_it[(long)p.x * DD + lane], acc);
    }
    acc += acc2;
    float y = bn;
#pragma unroll
    for (int k = 0; k < DD; ++k)
      y = fmaf(rdlane(acc, k), Wl[k * DD + lane], y);
    out[r * DD + lane] = fmaxf(y, 0.f);
  }
}

__global__ __launch_bounds__(256) void gnn_item_layer(
    const float* __restrict__ cur_it, const float* __restrict__ cur_u,
    const int* __restrict__ offsA, const int2* __restrict__ pairsA,
    const int* __restrict__ offsB, const int2* __restrict__ pairsB,
    const float* __restrict__ W, const float* __restrict__ bias,
    float* __restrict__ out) {
  __shared__ float Wl[DD * DD];
  for (int i = threadIdx.x; i < DD * DD; i += blockDim.x) Wl[i] = W[i];
  __syncthreads();
  const int lane = threadIdx.x & 63;
  const float bn = bias[lane];
  long wid = ((long)blockIdx.x * blockDim.x + threadIdx.x) >> 6;
  long nw = ((long)gridDim.x * blockDim.x) >> 6;
  for (long r = wid; r < I_N; r += nw) {
    float acc = cur_it[r * DD + lane], acc2 = 0.f;
    int j = offsA[r], j1 = offsA[r + 1];
    for (; j + 1 < j1; j += 2) {
      int2 p0 = pairsA[j], p1 = pairsA[j + 1];
      acc = fmaf(__int_as_float(p0.y), cur_it[(long)p0.x * DD + lane], acc);
      acc2 = fmaf(__int_as_float(p1.y), cur_it[(long)p1.x * DD + lane], acc2);
    }
    if (j < j1) {
      int2 p = pairsA[j];
      acc = fmaf(__int_as_float(p.y), cur_it[(long)p.x * DD + lane], acc);
    }
    j = offsB[r];
    j1 = offsB[r + 1];
    for (; j + 1 < j1; j += 2) {
      int2 p0 = pairsB[j], p1 = pairsB[j + 1];
      acc = fmaf(__int_as_float(p0.y), cur_u[(long)p0.x * DD + lane], acc);
      acc2 = fmaf(__int_as_float(p1.y), cur_u[(long)p1.x * DD + lane], acc2);
    }
    if (j < j1) {
      int2 p = pairsB[j];
      acc = fmaf(__int_as_float(p.y), cur_u[(long)p.x * DD + lane], acc);
    }
    acc += acc2;
    float y = bn;
#pragma unroll
    for (int k = 0; k < DD; ++k)
      y = fmaf(rdlane(acc, k), Wl[k * DD + lane], y);
    out[r * DD + lane] = fmaxf(y, 0.f);
  }
}

// layer-1 user output, only for the 8192 selected users
__global__ __launch_bounds__(256) void gnn_user_sel(
    const float* __restrict__ u_a, const float* __restrict__ it_a,
    const int* __restrict__ user_idx, const int* __restrict__ offs,
    const int2* __restrict__ pairs, const float* __restrict__ W,
    const float* __restrict__ bias, float* __restrict__ out) {
  __shared__ float Wl[DD * DD];
  for (int i = threadIdx.x; i < DD * DD; i += blockDim.x) Wl[i] = W[i];
  __syncthreads();
  const int lane = threadIdx.x & 63;
  const float bn = bias[lane];
  long wid = ((long)blockIdx.x * blockDim.x + threadIdx.x) >> 6;
  long nw = ((long)gridDim.x * blockDim.x) >> 6;
  for (long b = wid; b < BB; b += nw) {
    int r = user_idx[b];
    float acc = u_a[(long)r * DD + lane], acc2 = 0.f;
    int j = offs[r], j1 = offs[r + 1];
    for (; j + 1 < j1; j += 2) {
      int2 p0 = pairs[j], p1 = pairs[j + 1];
      acc = fmaf(__int_as_float(p0.y), it_a[(long)p0.x * DD + lane], acc);
      acc2 = fmaf(__int_as_float(p1.y), it_a[(long)p1.x * DD + lane], acc2);
    }
    if (j < j1) {
      int2 p = pairs[j];
      acc = fmaf(__int_as_float(p.y), it_a[(long)p.x * DD + lane], acc);
    }
    acc += acc2;
    float y = bn;
#pragma unroll
    for (int k = 0; k < DD; ++k)
      y = fmaf(rdlane(acc, k), Wl[k * DD + lane], y);
    out[b * DD + lane] = fmaxf(y, 0.f);
  }
}

// ---------------- sequence encode ----------------

__global__ __launch_bounds__(256) void seq_encode(
    const float* __restrict__ itf, const float* __restrict__ beh_emb,
    const float* __restrict__ t_w1, const float* __restrict__ t_b1,
    const float* __restrict__ t_w2, const float* __restrict__ t_b2,
    const float* __restrict__ ln_g, const float* __restrict__ ln_b,
    const float* __restrict__ delta, const int* __restrict__ items,
    const int* __restrict__ behs, float* __restrict__ seqx) {
  __shared__ float W2[DD * DD];
  for (int i = threadIdx.x; i < DD * DD; i += blockDim.x) W2[i] = t_w2[i];
  __syncthreads();
  const int lane = threadIdx.x & 63;
  const float w1 = t_w1[lane], b1 = t_b1[lane], b2 = t_b2[lane];
  const float g = ln_g[lane], bo = ln_b[lane];
  long wid = ((long)blockIdx.x * blockDim.x + threadIdx.x) >> 6;
  long nw = ((long)gridDim.x * blockDim.x) >> 6;
  const long NR = (long)BB * TT;
  for (long r = wid; r < NR; r += nw) {
    int it = items[r];
    int bh = behs[r];
    float x = itf[(long)it * DD + lane] + BEH_SCALE_ * beh_emb[bh * DD + lane];
    float tv = log1pf(delta[r]);
    float tmp = fmaxf(fmaf(tv, w1, b1), 0.f);
    float y = b2;
#pragma unroll
    for (int k = 0; k < DD; ++k)
      y = fmaf(rdlane(tmp, k), W2[k * DD + lane], y);
    x += y;
    float mu = wave_sum64(x) * (1.f / DD);
    float xc = x - mu;
    float var = wave_sum64(xc * xc) * (1.f / DD);
    float xo = xc * rsqrtf(var + LN_EPS_) * g + bo;
    seqx[r * DD + lane] = xo;
  }
}

// ---------------- GRU: wave owns 8 rows, h/x in registers, readlane bcast ----
#define GRW 8
__global__ __launch_bounds__(256) void gru_scan_rl(
    const float* __restrict__ seqx, const float* __restrict__ Wih,
    const float* __restrict__ Whh, const float* __restrict__ bih,
    const float* __restrict__ bhh, const int* __restrict__ seq_len,
    float* __restrict__ hfin) {
  __shared__ float sWih[DD * 192];
  __shared__ float sWhh[DD * 192];
  const int tid = threadIdx.x;
  for (int i = tid; i < DD * 192; i += 256) {
    sWih[i] = Wih[i];
    sWhh[i] = Whh[i];
  }
  __syncthreads();
  const int lane = tid & 63;
  const int wv = tid >> 6;
  const int row0 = blockIdx.x * 32 + wv * GRW;
  const float b_ir = bih[lane], b_iz = bih[64 + lane], b_in = bih[128 + lane];
  const float b_hr = bhh[lane], b_hz = bhh[64 + lane], b_hn = bhh[128 + lane];
  int sl[GRW];
  float h[GRW], xc[GRW], xn[GRW];
#pragma unroll
  for (int r = 0; r < GRW; ++r) {
    sl[r] = seq_len[row0 + r];
    h[r] = 0.f;
    xc[r] = seqx[((long)(row0 + r) * TT) * DD + lane];
  }
  for (int t = 0; t < TT; ++t) {
    if (t + 1 < TT) {
#pragma unroll
      for (int r = 0; r < GRW; ++r)
        xn[r] = seqx[((long)(row0 + r) * TT + (t + 1)) * DD + lane];
    }
    float aR[GRW], aZ[GRW], aNi[GRW], aNh[GRW];
#pragma unroll
    for (int r = 0; r < GRW; ++r) {
      aR[r] = b_ir + b_hr;
      aZ[r] = b_iz + b_hz;
      aNi[r] = b_in;
      aNh[r] = b_hn;
    }
#pragma unroll
    for (int k = 0; k < DD; ++k) {
      const float wir = sWih[k * 192 + lane];
      const float wiz = sWih[k * 192 + 64 + lane];
      const float win = sWih[k * 192 + 128 + lane];
      const float whr = sWhh[k * 192 + lane];
      const float whz = sWhh[k * 192 + 64 + lane];
      const float whn = sWhh[k * 192 + 128 + lane];
#pragma unroll
      for (int r = 0; r < GRW; ++r) {
        const float xv = rdlane(xc[r], k);
        const float hv = rdlane(h[r], k);
        aR[r] = fmaf(xv, wir, aR[r]);
        aR[r] = fmaf(hv, whr, aR[r]);
        aZ[r] = fmaf(xv, wiz, aZ[r]);
        aZ[r] = fmaf(hv, whz, aZ[r]);
        aNi[r] = fmaf(xv, win, aNi[r]);
        aNh[r] = fmaf(hv, whn, aNh[r]);
      }
    }
#pragma unroll
    for (int r = 0; r < GRW; ++r) {
      float rg = 1.f / (1.f + __expf(-aR[r]));
      float zg = 1.f / (1.f + __expf(-aZ[r]));
      float ng = tanhf(fmaf(rg, aNh[r], aNi[r]));
      float hn = fmaf(zg, h[r] - ng, ng);  // (1-z)*n + z*h
      h[r] = (t < sl[r]) ? hn : h[r];
    }
#pragma unroll
    for (int r = 0; r < GRW; ++r) xc[r] = xn[r];
  }
#pragma unroll
  for (int r = 0; r < GRW; ++r)
    hfin[(long)(row0 + r) * DD + lane] = h[r];
}

// ---------------- final scoring ----------------

__global__ __launch_bounds__(256) void final_score(
    const float* __restrict__ u_sel, const float* __restrict__ itf,
    const float* __restrict__ hfin, const float* __restrict__ ln_g,
    const float* __restrict__ ln_b, const int* __restrict__ pos_idx,
    const int* __restrict__ neg_idx, const int* __restrict__ pos_beh,
    float* __restrict__ out) {
  __shared__ float partial[4];
  const int lane = threadIdx.x & 63;
  const int wv = threadIdx.x >> 6;
  const float g = ln_g[lane], bo = ln_b[lane];
  float local = 0.f;
  int wid = blockIdx.x * 4 + wv;
  int nw = gridDim.x * 4;
  for (int r = wid; r < BB; r += nw) {
    float uf = u_sel[(long)r * DD + lane] + hfin[(long)r * DD + lane];
    float mu = wave_sum64(uf) * (1.f / DD);
    float xc = uf - mu;
    float var = wave_sum64(xc * xc) * (1.f / DD);
    float un = xc * rsqrtf(var + LN_EPS_) * g + bo;
    float pv = itf[(long)pos_idx[r] * DD + lane];
    float nv = itf[(long)neg_idx[r] * DD + lane];
    float ps = wave_sum64(un * pv);
    float ns = wave_sum64(un * nv);
    float n1 = wave_sum64(un * un);
    float n2 = wave_sum64(pv * pv);
    float n3 = wave_sum64(nv * nv);
    float d = ps - ns;
    float sp = fmaxf(-d, 0.f) + log1pf(__expf(-fabsf(d)));
    int pb = pos_beh[r];
    pb = pb < 0 ? 0 : (pb > 3 ? 3 : pb);
    float bw = pb == 0 ? 1.0f : (pb == 1 ? 1.25f : (pb == 2 ? 1.6f : 2.1f));
    local += sp * bw + REG_COEF_ * (sqrtf(n1) + sqrtf(n2) + sqrtf(n3));
  }
  if (lane == 0) partial[wv] = local;
  __syncthreads();
  if (threadIdx.x == 0) {
    float s = partial[0] + partial[1] + partial[2] + partial[3];
    atomicAdd(out, s * (1.f / BB));
  }
}

extern "C" void kernel_launch(void* const* d_in, const int* in_sizes, int n_in,
                              void* d_out, int out_size, void* d_ws,
                              size_t ws_size, hipStream_t stream) {
  const float* user_emb = (const float*)d_in[0];
  const float* item_emb = (const float*)d_in[1];
  const float* beh_emb = (const float*)d_in[2];
  const float* t_w1 = (const float*)d_in[3];
  const float* t_b1 = (const float*)d_in[4];
  const float* t_w2 = (const float*)d_in[5];
  const float* t_b2 = (const float*)d_in[6];
  const float* gru_w_ih = (const float*)d_in[7];
  const float* gru_w_hh = (const float*)d_in[8];
  const float* gru_b_ih = (const float*)d_in[9];
  const float* gru_b_hh = (const float*)d_in[10];
  const float* gnn_user_w = (const float*)d_in[11];
  const float* gnn_user_b = (const float*)d_in[12];
  const float* gnn_item_w = (const float*)d_in[13];
  const float* gnn_item_b = (const float*)d_in[14];
  const float* ln_g = (const float*)d_in[15];
  const float* ln_b = (const float*)d_in[16];
  const float* ui_vals = (const float*)d_in[17];
  const float* adj_vals = (const float*)d_in[18];
  const float* seq_delta = (const float*)d_in[19];
  const int* ui_rows = (const int*)d_in[20];
  const int* ui_cols = (const int*)d_in[21];
  const int* adj_rows = (const int*)d_in[22];
  const int* adj_cols = (const int*)d_in[23];
  const int* seq_items = (const int*)d_in[24];
  const int* seq_behaviors = (const int*)d_in[25];
  const int* seq_len = (const int*)d_in[26];
  const int* user_idx = (const int*)d_in[27];
  const int* pos_item_idx = (const int*)d_in[28];
  const int* neg_item_idx = (const int*)d_in[29];
  const int* pos_behavior = (const int*)d_in[30];

  float* ws = (float*)d_ws;
  float* u_a = ws;                              // 6.4M
  float* it_a = u_a + (long)U_N * DD;           // 3.2M
  float* it_b = it_a + (long)I_N * DD;          // 3.2M
  float* seqx = it_b + (long)I_N * DD;          // 15.73M
  float* hfin = seqx + (long)BB * TT * DD;      // 0.52M
  float* u_sel = hfin + (long)BB * DD;          // 0.52M
  float* end_f = u_sel + (long)BB * DD;

  int2* pairs_ui_row = (int2*)end_f;
  int2* pairs_ui_col = pairs_ui_row + N_EUI;
  int2* pairs_adj = pairs_ui_col + N_EUI;
  int* offs_ui_row = (int*)(pairs_adj + N_EII);
  int* offs_ui_col = offs_ui_row + (U_N + 1);
  int* offs_adj = offs_ui_col + (I_N + 1);
  int* cur_ui_row = offs_adj + (I_N + 1);
  int* cur_ui_col = cur_ui_row + U_N;
  int* cur_adj = cur_ui_col + I_N;

  hipMemsetAsync(d_out, 0, (size_t)out_size * sizeof(float), stream);
  hipMemsetAsync(cur_ui_row, 0, (size_t)(U_N + I_N + I_N) * sizeof(int),
                 stream);

  // ---- CSR build ----
  hist_kernel<<<2048, 256, 0, stream>>>(ui_rows, N_EUI, cur_ui_row);
  hist_kernel<<<2048, 256, 0, stream>>>(ui_cols, N_EUI, cur_ui_col);
  hist_kernel<<<1024, 256, 0, stream>>>(adj_rows, N_EII, cur_adj);
  ex_scan<<<1, 1024, 0, stream>>>(cur_ui_row, U_N, offs_ui_row, cur_ui_row);
  ex_scan<<<1, 1024, 0, stream>>>(cur_ui_col, I_N, offs_ui_col, cur_ui_col);
  ex_scan<<<1, 1024, 0, stream>>>(cur_adj, I_N, offs_adj, cur_adj);
  csr_fill<<<2048, 256, 0, stream>>>(ui_rows, ui_cols, ui_vals, N_EUI,
                                     cur_ui_row, pairs_ui_row);
  csr_fill<<<2048, 256, 0, stream>>>(ui_cols, ui_rows, ui_vals, N_EUI,
                                     cur_ui_col, pairs_ui_col);
  csr_fill<<<1024, 256, 0, stream>>>(adj_rows, adj_cols, adj_vals, N_EII,
                                     cur_adj, pairs_adj);

  // ---- GNN layer 0 (all users + all items) ----
  gnn_user_layer<<<2048, 256, 0, stream>>>(user_emb, item_emb, offs_ui_row,
                                           pairs_ui_row, gnn_user_w,
                                           gnn_user_b, u_a);
  gnn_item_layer<<<2048, 256, 0, stream>>>(item_emb, user_emb, offs_adj,
                                           pairs_adj, offs_ui_col,
                                           pairs_ui_col, gnn_item_w,
                                           gnn_item_b, it_a);
  // ---- GNN layer 1 (all items; users only where needed) ----
  gnn_item_layer<<<2048, 256, 0, stream>>>(it_a, u_a, offs_adj, pairs_adj,
                                           offs_ui_col, pairs_ui_col,
                                           gnn_item_w + DD * DD,
                                           gnn_item_b + DD, it_b);
  gnn_user_sel<<<512, 256, 0, stream>>>(u_a, it_a, user_idx, offs_ui_row,
                                        pairs_ui_row, gnn_user_w + DD * DD,
                                        gnn_user_b + DD, u_sel);

  // ---- sequence encoding ----
  seq_encode<<<2048, 256, 0, stream>>>(it_b, beh_emb, t_w1, t_b1, t_w2, t_b2,
                                       ln_g, ln_b, seq_delta, seq_items,
                                       seq_behaviors, seqx);

  // ---- GRU scan ----
  gru_scan_rl<<<BB / 32, 256, 0, stream>>>(seqx, gru_w_ih, gru_w_hh, gru_b_ih,
                                           gru_b_hh, seq_len, hfin);

  // ---- final scoring ----
  final_score<<<256, 256, 0, stream>>>(u_sel, it_b, hfin, ln_g, ln_b,
                                       pos_item_idx, neg_item_idx,
                                       pos_behavior, (float*)d_out);
}